// Round 1
// baseline (178.929 us; speedup 1.0000x reference)
//
#include <hip/hip_runtime.h>

// DirectionalConv3d: B=8, C_IN=C_OUT=64, T=R=32, CO=32
// v2 design: two passes.
//  pass 1 (prep): x fp32 [b][ch][s] -> bf16 [b][s][ch] in d_ws (+ bf16 weights).
//  pass 2 (conv2): LDS-free, barrier-free. All 7 taps gather A-fragments as
//    single contiguous 16B loads from the transposed bf16 x (per-lane masked,
//    clamped rows). B-fragments from the 56KB bf16 weight table (L1/L2-hot).
// Tier 2 fallback: previous fused LDS kernel (ws >= 56KB only).
// Tier 3 fallback: fp32 direct.

#define SB 32768   // spatial per batch (T*R*CO)
#define CIN 64
#define COUT 64
#define NB 8

typedef short s16x8 __attribute__((ext_vector_type(8)));
typedef __bf16 bf16x8 __attribute__((ext_vector_type(8)));
typedef float f32x4 __attribute__((ext_vector_type(4)));

__device__ __forceinline__ unsigned f2bf(float f) {
    unsigned u = __float_as_uint(f);
    u += 0x7FFFu + ((u >> 16) & 1u);   // round-to-nearest-even
    return u >> 16;
}
__device__ __forceinline__ unsigned pk2(float lo, float hi) {
    return f2bf(lo) | (f2bf(hi) << 16);
}

// ---------------- weight prep: fp32 -> bf16, [tap][o][i] ----------------
__global__ __launch_bounds__(256) void wprep_kernel(const float* __restrict__ w0,
                            const float* __restrict__ w1, const float* __restrict__ w2,
                            const float* __restrict__ w3, const float* __restrict__ w4,
                            const float* __restrict__ w5, const float* __restrict__ w6,
                            unsigned short* __restrict__ ws) {
    int tap = blockIdx.x;
    int tid = threadIdx.x;
    const float* w = (tap == 0) ? w0 : (tap == 1) ? w1 : (tap == 2) ? w2
                   : (tap == 3) ? w3 : (tap == 4) ? w4 : (tap == 5) ? w5 : w6;
    unsigned p[8];
#pragma unroll
    for (int j = 0; j < 8; ++j)
        p[j] = pk2(w[tid * 16 + 2 * j], w[tid * 16 + 2 * j + 1]);
    uint4* dp = (uint4*)(ws + tap * 4096 + tid * 16);
    dp[0] = make_uint4(p[0], p[1], p[2], p[3]);
    dp[1] = make_uint4(p[4], p[5], p[6], p[7]);
}

// ---------------- pass 1: weights + x transpose/convert ----------------
// grid 1031 = 1024 x-tiles (8 b x 128 s-tiles of 256) + 7 weight taps.
// x-tile: thread owns row s = sblk+tid; reads 64 channels (coalesced across
// lanes per channel), packs to bf16, bounces through swizzled LDS so the
// global write is fully coalesced uint4 (1KB/instr per wave).
__global__ __launch_bounds__(256) void prep_kernel(const float* __restrict__ x,
                            const float* __restrict__ w0, const float* __restrict__ w1,
                            const float* __restrict__ w2, const float* __restrict__ w3,
                            const float* __restrict__ w4, const float* __restrict__ w5,
                            const float* __restrict__ w6,
                            unsigned short* __restrict__ ws) {
    int bid = blockIdx.x;
    int tid = threadIdx.x;
    if (bid >= 1024) {                 // weight blocks
        int tap = bid - 1024;
        const float* w = (tap == 0) ? w0 : (tap == 1) ? w1 : (tap == 2) ? w2
                       : (tap == 3) ? w3 : (tap == 4) ? w4 : (tap == 5) ? w5 : w6;
        unsigned p[8];
#pragma unroll
        for (int j = 0; j < 8; ++j)
            p[j] = pk2(w[tid * 16 + 2 * j], w[tid * 16 + 2 * j + 1]);
        uint4* dp = (uint4*)(ws + tap * 4096 + tid * 16);
        dp[0] = make_uint4(p[0], p[1], p[2], p[3]);
        dp[1] = make_uint4(p[4], p[5], p[6], p[7]);
        return;
    }
    __shared__ uint4 l[2048];          // 32 KB, 16B-chunk xor swizzle
    int lbid = ((bid & 7) << 7) | (bid >> 3);   // same XCD chunking as conv2
    int b = lbid >> 7;
    int sblk = (lbid & 127) << 8;
    unsigned short* xq = ws + 7 * 4096;
    const float* xp = x + (size_t)b * CIN * SB + sblk + tid;
#pragma unroll
    for (int c = 0; c < 4; ++c) {      // 16 channels per iteration
        unsigned pk[8];
#pragma unroll
        for (int u = 0; u < 8; ++u)
            pk[u] = pk2(xp[(size_t)(c * 16 + 2 * u) * SB],
                        xp[(size_t)(c * 16 + 2 * u + 1) * SB]);
        l[tid * 8 + ((2 * c) ^ (tid & 7))] = make_uint4(pk[0], pk[1], pk[2], pk[3]);
        l[tid * 8 + ((2 * c + 1) ^ (tid & 7))] = make_uint4(pk[4], pk[5], pk[6], pk[7]);
    }
    __syncthreads();
    uint4* dst = (uint4*)(xq + ((size_t)b * SB + sblk) * 64);
#pragma unroll
    for (int k = 0; k < 8; ++k) {
        int idx = k * 256 + tid;
        int row = idx >> 3;
        int col = idx & 7;
        dst[idx] = l[row * 8 + (col ^ (row & 7))];
    }
}

// ---------------- pass 2: LDS-free gather conv ----------------
// grid 1024 = 8 b x 128 s-tiles of 256 (XCD-chunked: batch b pinned to XCD b).
// Block 256 thr = 4 waves; wave: 64 s x 64 o = 4x4 grid of 16x16 tiles,
// K=448 via mfma_f32_16x16x32_bf16. A-fragments: one 16B load each from
// bf16 [b][s][ch]; per-instr footprint = 16 full 64B lines (coalesced).
__global__ __launch_bounds__(256) void conv2_kernel(const unsigned short* __restrict__ xq,
                                                    const unsigned short* __restrict__ wq,
                                                    float* __restrict__ out) {
    int bid = blockIdx.x;
    int lbid = ((bid & 7) << 7) | (bid >> 3);   // bijective: 1024 % 8 == 0
    int b = lbid >> 7;
    int sblk = (lbid & 127) << 8;
    int tid = threadIdx.x;
    int lane = tid & 63;
    int wv = tid >> 6;
    int lo = lane & 15;
    int quad = lane >> 4;
    int sbase = sblk + wv * 64;
    int t = sblk >> 10;                          // uniform within block
    const unsigned short* xb = xq + (size_t)b * (CIN * SB);

    f32x4 acc[4][4];
#pragma unroll
    for (int mt = 0; mt < 4; ++mt)
#pragma unroll
        for (int nt = 0; nt < 4; ++nt)
            acc[mt][nt] = (f32x4){0.f, 0.f, 0.f, 0.f};

    int s_m[4], r_m[4], c_m[4];
#pragma unroll
    for (int mt = 0; mt < 4; ++mt) {
        int s = sbase + mt * 16 + lo;            // A row: m = lane&15
        s_m[mt] = s;
        r_m[mt] = (s >> 5) & 31;
        c_m[mt] = s & 31;
    }

    auto load_b = [&](const unsigned short* wt, int ks, int nt) -> bf16x8 {
        const unsigned short* bp = wt + (nt * 16 + lo) * 64 + ks * 32 + quad * 8;
        return __builtin_bit_cast(bf16x8, *(const s16x8*)bp);
    };

    auto run_tap = [&](int tap, int d, const bool ok[4]) {
        const unsigned short* wt = wq + tap * 4096;
#pragma unroll
        for (int ks = 0; ks < 2; ++ks) {
            bf16x8 bf[4];
#pragma unroll
            for (int nt = 0; nt < 4; ++nt) bf[nt] = load_b(wt, ks, nt);
#pragma unroll
            for (int mt = 0; mt < 4; ++mt) {
                int s = s_m[mt] + d;
                s = s < 0 ? 0 : s;               // clamped rows feed masked lanes only
                s = s > SB - 1 ? SB - 1 : s;
                s16x8 raw = *(const s16x8*)(xb + (size_t)s * 64 + ks * 32 + quad * 8);
                s16x8 zz = {0, 0, 0, 0, 0, 0, 0, 0};
                raw = ok[mt] ? raw : zz;
                bf16x8 af = __builtin_bit_cast(bf16x8, raw);
#pragma unroll
                for (int nt = 0; nt < 4; ++nt)
                    acc[mt][nt] = __builtin_amdgcn_mfma_f32_16x16x32_bf16(af, bf[nt], acc[mt][nt], 0, 0, 0);
            }
        }
    };

    {
        bool ok_all[4] = {true, true, true, true};
        run_tap(0, 0, ok_all);                   // self
        if (t > 0)  run_tap(1, -1024, ok_all);   // t-1
        if (t < 31) run_tap(2, 1024, ok_all);    // t+1
    }
    {
        bool ok[4];
#pragma unroll
        for (int mt = 0; mt < 4; ++mt) ok[mt] = (r_m[mt] > 0);
        run_tap(3, -32, ok);                     // r-1
#pragma unroll
        for (int mt = 0; mt < 4; ++mt) ok[mt] = (r_m[mt] < 31);
        run_tap(4, 32, ok);                      // r+1
#pragma unroll
        for (int mt = 0; mt < 4; ++mt) ok[mt] = (c_m[mt] > 0);
        run_tap(5, -1, ok);                      // c-1
#pragma unroll
        for (int mt = 0; mt < 4; ++mt) ok[mt] = (c_m[mt] < 31);
        run_tap(6, 1, ok);                       // c+1
    }

    // D layout: col(n=o) = lane&15, row(m=s) = quad*4 + reg -> full 64B lines per wave
#pragma unroll
    for (int mt = 0; mt < 4; ++mt) {
#pragma unroll
        for (int nt = 0; nt < 4; ++nt) {
            int o = nt * 16 + lo;
            size_t off = ((size_t)(b * COUT + o)) * SB + sbase + mt * 16 + quad * 4;
            *(f32x4*)(out + off) = acc[mt][nt];
        }
    }
}

// ---------------- tier-2 fallback: previous fused LDS kernel ----------------
__global__ __launch_bounds__(256) void conv_kernel(const float* __restrict__ x,
                                                   const unsigned short* __restrict__ wq,
                                                   float* __restrict__ out) {
    __shared__ uint4 alds[2560];  // 40 KB: rows sblk-32 .. sblk+288, 16B-chunk xor swizzle
    int bid = blockIdx.x;
    int b = bid >> 7;
    int sblk = (bid & 127) << 8;
    int tid = threadIdx.x;
    const float* xb = x + (size_t)b * CIN * SB;

    {
        int rl = 32 + tid;
        const float* xp = xb + sblk + tid;
#pragma unroll
        for (int c = 0; c < 4; ++c) {
            unsigned pk[8];
#pragma unroll
            for (int u = 0; u < 8; ++u)
                pk[u] = pk2(xp[(size_t)(c * 16 + 2 * u) * SB],
                            xp[(size_t)(c * 16 + 2 * u + 1) * SB]);
            alds[rl * 8 + ((2 * c) ^ (rl & 7))] = make_uint4(pk[0], pk[1], pk[2], pk[3]);
            alds[rl * 8 + ((2 * c + 1) ^ (rl & 7))] = make_uint4(pk[4], pk[5], pk[6], pk[7]);
        }
    }
    {
        int hrow = tid & 63;
        int rl = (hrow < 32) ? hrow : hrow + 256;
        int s = sblk - 32 + rl;
        s = max(0, min(SB - 1, s));
        int ic = tid >> 6;
        const float* xp = xb + s + (size_t)(ic * 16) * SB;
        unsigned pk[8];
#pragma unroll
        for (int u = 0; u < 8; ++u)
            pk[u] = pk2(xp[(size_t)(2 * u) * SB], xp[(size_t)(2 * u + 1) * SB]);
        alds[rl * 8 + ((2 * ic) ^ (rl & 7))] = make_uint4(pk[0], pk[1], pk[2], pk[3]);
        alds[rl * 8 + ((2 * ic + 1) ^ (rl & 7))] = make_uint4(pk[4], pk[5], pk[6], pk[7]);
    }
    __syncthreads();

    int lane = tid & 63;
    int wv = tid >> 6;
    int lo = lane & 15;
    int quad = lane >> 4;
    int sbase = sblk + wv * 64;
    int t = sblk >> 10;

    f32x4 acc[4][4];
#pragma unroll
    for (int mt = 0; mt < 4; ++mt)
#pragma unroll
        for (int nt = 0; nt < 4; ++nt)
            acc[mt][nt] = (f32x4){0.f, 0.f, 0.f, 0.f};

    int r_m[4], c_m[4], rl[4];
#pragma unroll
    for (int mt = 0; mt < 4; ++mt) {
        int s = sbase + mt * 16 + lo;
        r_m[mt] = (s >> 5) & 31;
        c_m[mt] = s & 31;
        rl[mt] = s - sblk + 32;
    }

    auto load_b = [&](const unsigned short* wt, int ks, int nt) -> bf16x8 {
        const unsigned short* bp = wt + (nt * 16 + lo) * 64 + ks * 32 + quad * 8;
        return __builtin_bit_cast(bf16x8, *(const s16x8*)bp);
    };

    auto run_tap_lds = [&](int tap, int d, const bool ok[4]) {
        const unsigned short* wt = wq + tap * 4096;
#pragma unroll
        for (int ks = 0; ks < 2; ++ks) {
            bf16x8 bf[4];
#pragma unroll
            for (int nt = 0; nt < 4; ++nt) bf[nt] = load_b(wt, ks, nt);
            int j = ks * 4 + quad;
#pragma unroll
            for (int mt = 0; mt < 4; ++mt) {
                int row = rl[mt] + d;
                s16x8 raw = *((const s16x8*)alds + row * 8 + (j ^ (row & 7)));
                s16x8 zz = {0, 0, 0, 0, 0, 0, 0, 0};
                raw = ok[mt] ? raw : zz;
                bf16x8 af = __builtin_bit_cast(bf16x8, raw);
#pragma unroll
                for (int nt = 0; nt < 4; ++nt)
                    acc[mt][nt] = __builtin_amdgcn_mfma_f32_16x16x32_bf16(af, bf[nt], acc[mt][nt], 0, 0, 0);
            }
        }
    };

    auto run_tap_gather = [&](int tap, int d) {
        const unsigned short* wt = wq + tap * 4096;
#pragma unroll
        for (int ks = 0; ks < 2; ++ks) {
            bf16x8 bf[4];
#pragma unroll
            for (int nt = 0; nt < 4; ++nt) bf[nt] = load_b(wt, ks, nt);
            const float* gp = xb + (size_t)(ks * 32 + quad * 8) * SB + d;
#pragma unroll
            for (int mt = 0; mt < 4; ++mt) {
                const float* ap = gp + sbase + mt * 16 + lo;
                unsigned pk[4];
#pragma unroll
                for (int u = 0; u < 4; ++u)
                    pk[u] = pk2(ap[(size_t)(2 * u) * SB], ap[(size_t)(2 * u + 1) * SB]);
                uint4 v = make_uint4(pk[0], pk[1], pk[2], pk[3]);
                bf16x8 af = __builtin_bit_cast(bf16x8, v);
#pragma unroll
                for (int nt = 0; nt < 4; ++nt)
                    acc[mt][nt] = __builtin_amdgcn_mfma_f32_16x16x32_bf16(af, bf[nt], acc[mt][nt], 0, 0, 0);
            }
        }
    };

    {
        bool ok_all[4] = {true, true, true, true};
        run_tap_lds(0, 0, ok_all);
    }
    if (t > 0)  run_tap_gather(1, -1024);
    if (t < 31) run_tap_gather(2, 1024);
    {
        bool ok[4];
#pragma unroll
        for (int mt = 0; mt < 4; ++mt) ok[mt] = (r_m[mt] > 0);
        run_tap_lds(3, -32, ok);
#pragma unroll
        for (int mt = 0; mt < 4; ++mt) ok[mt] = (r_m[mt] < 31);
        run_tap_lds(4, 32, ok);
#pragma unroll
        for (int mt = 0; mt < 4; ++mt) ok[mt] = (c_m[mt] > 0);
        run_tap_lds(5, -1, ok);
#pragma unroll
        for (int mt = 0; mt < 4; ++mt) ok[mt] = (c_m[mt] < 31);
        run_tap_lds(6, 1, ok);
    }

#pragma unroll
    for (int mt = 0; mt < 4; ++mt) {
#pragma unroll
        for (int nt = 0; nt < 4; ++nt) {
            int o = nt * 16 + lo;
            size_t off = ((size_t)(b * COUT + o)) * SB + sbase + mt * 16 + quad * 4;
            *(f32x4*)(out + off) = acc[mt][nt];
        }
    }
}

// ---------------- tier-3 fallback: fp32 direct ----------------
__global__ void fallback_kernel(const float* __restrict__ x,
                                const float* __restrict__ w0, const float* __restrict__ w1,
                                const float* __restrict__ w2, const float* __restrict__ w3,
                                const float* __restrict__ w4, const float* __restrict__ w5,
                                const float* __restrict__ w6,
                                float* __restrict__ out) {
    int bid = blockIdx.x;
    int b = bid >> 11;
    int og = (bid >> 7) & 15;
    int sblk = (bid & 127) << 8;
    int tid = threadIdx.x;
    __shared__ float wl[7][4][64];
    const float* wp[7] = {w0, w1, w2, w3, w4, w5, w6};
    for (int k = tid; k < 7 * 4 * 64; k += 256) {
        int tap = k >> 8, oo = (k >> 6) & 3, i = k & 63;
        wl[tap][oo][i] = wp[tap][(og * 4 + oo) * 64 + i];
    }
    __syncthreads();
    int s = sblk + tid;
    int t = s >> 10, r = (s >> 5) & 31, c = s & 31;
    const float* xb = x + (size_t)b * CIN * SB + s;
    float a0 = 0, a1 = 0, a2 = 0, a3 = 0;
    for (int i = 0; i < 64; ++i) {
        const float* xi = xb + (size_t)i * SB;
        float vs = xi[0];
        float vtp = (t > 0) ? xi[-1024] : 0.f;
        float vtm = (t < 31) ? xi[1024] : 0.f;
        float vrp = (r > 0) ? xi[-32] : 0.f;
        float vrm = (r < 31) ? xi[32] : 0.f;
        float vcp = (c > 0) ? xi[-1] : 0.f;
        float vcm = (c < 31) ? xi[1] : 0.f;
        a0 += wl[0][0][i] * vs + wl[1][0][i] * vtp + wl[2][0][i] * vtm + wl[3][0][i] * vrp + wl[4][0][i] * vrm + wl[5][0][i] * vcp + wl[6][0][i] * vcm;
        a1 += wl[0][1][i] * vs + wl[1][1][i] * vtp + wl[2][1][i] * vtm + wl[3][1][i] * vrp + wl[4][1][i] * vrm + wl[5][1][i] * vcp + wl[6][1][i] * vcm;
        a2 += wl[0][2][i] * vs + wl[1][2][i] * vtp + wl[2][2][i] * vtm + wl[3][2][i] * vrp + wl[4][2][i] * vrm + wl[5][2][i] * vcp + wl[6][2][i] * vcm;
        a3 += wl[0][3][i] * vs + wl[1][3][i] * vtp + wl[2][3][i] * vtm + wl[3][3][i] * vrp + wl[4][3][i] * vrm + wl[5][3][i] * vcp + wl[6][3][i] * vcm;
    }
    size_t obase = ((size_t)b * COUT + og * 4) * SB + s;
    out[obase] = a0;
    out[obase + SB] = a1;
    out[obase + 2 * (size_t)SB] = a2;
    out[obase + 3 * (size_t)SB] = a3;
}

extern "C" void kernel_launch(void* const* d_in, const int* in_sizes, int n_in,
                              void* d_out, int out_size, void* d_ws, size_t ws_size,
                              hipStream_t stream) {
    const float* x = (const float*)d_in[0];
    const float* w0 = (const float*)d_in[1];
    const float* w1 = (const float*)d_in[2];
    const float* w2 = (const float*)d_in[3];
    const float* w3 = (const float*)d_in[4];
    const float* w4 = (const float*)d_in[5];
    const float* w5 = (const float*)d_in[6];
    const float* w6 = (const float*)d_in[7];
    float* out = (float*)d_out;

    size_t need_w = (size_t)7 * 4096 * 2;                        // 56 KB weights
    size_t need_full = need_w + (size_t)NB * CIN * SB * 2;       // + 32 MB bf16 x
    if (d_ws != nullptr && ws_size >= need_full) {
        unsigned short* wsp = (unsigned short*)d_ws;
        prep_kernel<<<1031, 256, 0, stream>>>(x, w0, w1, w2, w3, w4, w5, w6, wsp);
        conv2_kernel<<<1024, 256, 0, stream>>>(wsp + 7 * 4096, wsp, out);
    } else if (d_ws != nullptr && ws_size >= need_w) {
        unsigned short* wsp = (unsigned short*)d_ws;
        wprep_kernel<<<7, 256, 0, stream>>>(w0, w1, w2, w3, w4, w5, w6, wsp);
        conv_kernel<<<1024, 256, 0, stream>>>(x, wsp, out);
    } else {
        fallback_kernel<<<8 * 16 * 128, 256, 0, stream>>>(x, w0, w1, w2, w3, w4, w5, w6, out);
    }
}